// Round 4
// baseline (221.026 us; speedup 1.0000x reference)
//
#include <hip/hip_runtime.h>
#include <math.h>

typedef __attribute__((ext_vector_type(8)))  __bf16   bf16x8;
typedef __attribute__((ext_vector_type(4)))  float    f32x4;
typedef __attribute__((ext_vector_type(16))) float    f32x16;
typedef __attribute__((ext_vector_type(4)))  unsigned u32x4;
typedef __attribute__((ext_vector_type(2)))  unsigned u32x2;

__device__ __forceinline__ unsigned short f2bf(float f) {
    unsigned u = __builtin_bit_cast(unsigned, f);
    u += 0x7fffu + ((u >> 16) & 1u);
    return (unsigned short)(u >> 16);
}
__device__ __forceinline__ float bf2f(unsigned short b) {
    unsigned u = ((unsigned)b) << 16;
    return __builtin_bit_cast(float, u);
}
__device__ __forceinline__ unsigned swz3(int key) { return (unsigned)((key ^ (key >> 3)) & 7); }
__device__ __forceinline__ bf16x8 ldfrag(const char* p) { return __builtin_bit_cast(bf16x8, *(const u32x4*)p); }

// ---------------------------------------------------------------------------
// prep = wconv (blocks 0..199) + x0conv (blocks 200..327)
// wt layout (elements): [0] WT0[64][32]  [2048] WT1[64][256]
//                       [18432] WT2[64][256]  [34816] WT3[64][256] (rows>=4 zero)
__global__ __launch_bounds__(256)
void prep(const float* __restrict__ W0, const float* __restrict__ W1,
          const float* __restrict__ W2, const float* __restrict__ W3,
          const float* __restrict__ x,
          unsigned short* __restrict__ wt,
          unsigned short* __restrict__ xT0, unsigned short* __restrict__ xR0)
{
    const int blk = blockIdx.x, t = threadIdx.x;
    if (blk < 200) {
        int id = blk * 256 + t;
        if (id >= 51200) return;
        float v; size_t dst;
        if (id < 2048)       { int h = id >> 5, f = id & 31;              v = W0[f*64 + h]; dst = (size_t)h*32 + f; }
        else if (id < 18432) { int j = id - 2048;  int h = j >> 8, f = j & 255; v = W1[f*64 + h]; dst = 2048  + (size_t)h*256 + f; }
        else if (id < 34816) { int j = id - 18432; int h = j >> 8, f = j & 255; v = W2[f*64 + h]; dst = 18432 + (size_t)h*256 + f; }
        else                 { int j = id - 34816; int h = j >> 8, f = j & 255; v = (h < 4) ? W3[f*4 + h] : 0.f; dst = 34816 + (size_t)h*256 + f; }
        wt[dst] = f2bf(v);
    } else {
        int id = (blk - 200) * 256 + t;   // 32768 = 32*1024
        int b = id >> 10, j = id & 1023;
        const float* s = x + (size_t)id * 16;
        unsigned pk[8];
#pragma unroll
        for (int f = 0; f < 16; f += 2) {
            unsigned short h0 = f2bf(s[f]);
            unsigned short h1 = f2bf(s[f + 1]);
            xT0[((size_t)b*16 + f    )*1024 + j] = h0;
            xT0[((size_t)b*16 + f + 1)*1024 + j] = h1;
            pk[f >> 1] = (unsigned)h0 | ((unsigned)h1 << 16);
        }
        u32x4* d = (u32x4*)(xR0 + (size_t)id * 16);
        u32x4 v0 = {pk[0], pk[1], pk[2], pk[3]};
        u32x4 v1 = {pk[4], pk[5], pk[6], pk[7]};
        d[0] = v0; d[1] = v1;
    }
}

// ---------------------------------------------------------------------------
// tgen: P[b][i][j] = round_bf16( round_bf16(exp(exp(-d_ij*p))) / rowsum )
// block = (i-tile of 16 rows, sample). thread (r=t>>4, jg=t&15): 8 passes of
// 8 consecutive j (coalesced 16B stores).
__global__ __launch_bounds__(256, 4)
void tgen(const float* __restrict__ coords, const float* __restrict__ psq,
          unsigned short* __restrict__ Tg)
{
    __shared__ float4 sc[1024];
    const int t = threadIdx.x;
    const int b = blockIdx.y;
    const int i0 = blockIdx.x * 16;
    for (int k = t; k < 1024; k += 256) {
        const float* c = coords + ((size_t)b*1024 + k)*3;
        float cx = c[0], cy = c[1], cz = c[2];
        sc[k] = make_float4(cx, cy, cz, cx*cx + cy*cy + cz*cz);
    }
    __syncthreads();
    const float p = psq[0];
    const int r = t >> 4, jg = t & 15;
    const float4 ci = sc[i0 + r];
    u32x4 pk0, pk1, pk2, pk3, pk4, pk5, pk6, pk7;
    u32x4* pk[8] = {&pk0,&pk1,&pk2,&pk3,&pk4,&pk5,&pk6,&pk7};
    float rsum = 0.f;
#pragma unroll
    for (int pp = 0; pp < 8; ++pp) {
        const int jb = pp*128 + jg*8;
        u32x4 v;
#pragma unroll
        for (int e = 0; e < 4; ++e) {
            float4 cj0 = sc[jb + 2*e], cj1 = sc[jb + 2*e + 1];
            float d0 = ci.w + cj0.w - 2.f*(ci.x*cj0.x + ci.y*cj0.y + ci.z*cj0.z);
            float d1 = ci.w + cj1.w - 2.f*(ci.x*cj1.x + ci.y*cj1.y + ci.z*cj1.z);
            unsigned short h0 = f2bf(__expf(__expf(-d0 * p)));
            unsigned short h1 = f2bf(__expf(__expf(-d1 * p)));
            rsum += bf2f(h0) + bf2f(h1);
            v[e] = (unsigned)h0 | ((unsigned)h1 << 16);
        }
        *pk[pp] = v;
    }
    rsum += __shfl_xor(rsum, 1);
    rsum += __shfl_xor(rsum, 2);
    rsum += __shfl_xor(rsum, 4);
    rsum += __shfl_xor(rsum, 8);
    const float rinv = 1.f / rsum;
    unsigned short* dst = Tg + ((size_t)(b*1024 + i0 + r))*1024;
#pragma unroll
    for (int pp = 0; pp < 8; ++pp) {
        u32x4 u = *pk[pp], v;
#pragma unroll
        for (int e = 0; e < 4; ++e) {
            unsigned uu = u[e];
            float lo = bf2f((unsigned short)(uu & 0xffffu)) * rinv;
            float hi = bf2f((unsigned short)(uu >> 16)) * rinv;
            v[e] = (unsigned)f2bf(lo) | ((unsigned)f2bf(hi) << 16);
        }
        *(u32x4*)(dst + pp*128 + jg*8) = v;
    }
}

// ---------------------------------------------------------------------------
// MODE 0: F=16 first block. MODE 1: F=128 mid. MODE 2: F=128 final.
// All stage pre-normalized P from global (reg-staged double buffer).
template<int MODE>
__global__ __launch_bounds__(256, MODE ? 3 : 4)
void gcn_block(const unsigned short* __restrict__ xT, const unsigned short* __restrict__ xR,
               const unsigned short* __restrict__ Tg,
               const unsigned short* __restrict__ WThi,
               const float* __restrict__ gamma, const float* __restrict__ beta,
               const float* __restrict__ bias,
               unsigned short* __restrict__ oxT, unsigned short* __restrict__ oxR,
               float* __restrict__ part)
{
    constexpr int SMEM = MODE ? 49664 : 20480;
    __shared__ char smem[SMEM];
    // MODE1/2 layout
    constexpr int XTB  = 0;           // x^T dbuf [2][128][128B]
    constexpr int TTB  = 32 * 1024;   // T dbuf [2][64][128B]
    constexpr int SPT  = 49152;
    constexpr int YL   = 0;           // dense: y [64][256B]
    constexpr int XI   = 16 * 1024;   // dense: xi [64][256B]
    constexpr int WTB  = 32 * 1024;   // dense: WT [64][256B]
    // MODE0 layout
    constexpr int XT0B = 0;           // x^T dbuf [2][16][128B]
    constexpr int TT0B = 4096;        // T dbuf [2][64][128B]
    constexpr int C0O  = 0;           // concat [64][64B]
    constexpr int W0H  = 4096;        // W0T [64][64B]
    constexpr int ZT   = 0;           // z fp32 [64][65]

    const int t = threadIdx.x;
    const int l = t & 63;
    const int w = t >> 6;
    const int b  = blockIdx.y;
    const int it = blockIdx.x;
    const int i0g = it * 64;
    const int m31 = l & 31, kg = l >> 5;
    const int m15 = l & 15, kg4 = l >> 4;
    const int wf = w >> 1, wi = w & 1;
    float bv = 0.f;
    if constexpr (MODE != 2) bv = bias[0];

    int fA0 = 0, fA1 = 0, iB = 0;
    if constexpr (MODE) { fA0 = wf*64 + m31; fA1 = fA0 + 32; iB = wi*32 + m31; }
    else                { fA0 = m15;                          iB = w*16 + m15; }

    f32x16 acc0, acc1; f32x4 acc4;
#pragma unroll
    for (int r = 0; r < 16; ++r) { acc0[r] = 0.f; acc1[r] = 0.f; }
#pragma unroll
    for (int r = 0; r < 4; ++r) acc4[r] = 0.f;

    // ================= main loop: y^T = x^T @ P^T =================
    const int sti = t >> 2, stc = t & 3;
    const unsigned short* gtb = Tg + ((size_t)(b*1024 + i0g + sti))*1024 + stc*16;
    u32x4 rt0 = *(const u32x4*)(gtb);
    u32x4 rt1 = *(const u32x4*)(gtb + 8);
    const unsigned swt = swz3(sti) << 4;
    const unsigned sB  = swz3(iB) << 4;

    if constexpr (MODE) {
        const int sf = t >> 1, shf = t & 1;
        const unsigned short* gxb = xT + ((size_t)b*128 + sf)*1024 + shf*32;
        u32x4 rx0, rx1, rx2, rx3;
        rx0 = *(const u32x4*)(gxb);      rx1 = *(const u32x4*)(gxb + 8);
        rx2 = *(const u32x4*)(gxb + 16); rx3 = *(const u32x4*)(gxb + 24);
        const unsigned swx = swz3(sf) << 4;
        const unsigned sA0 = swz3(fA0) << 4;
        const unsigned sA1 = swz3(fA1) << 4;

        for (int jt = 0; jt < 16; ++jt) {
            const int p = jt & 1;
            {
                char* xrow = smem + XTB + p*16384 + sf*128;
                *(u32x4*)(xrow + ((shf*64 +  0) ^ swx)) = rx0;
                *(u32x4*)(xrow + ((shf*64 + 16) ^ swx)) = rx1;
                *(u32x4*)(xrow + ((shf*64 + 32) ^ swx)) = rx2;
                *(u32x4*)(xrow + ((shf*64 + 48) ^ swx)) = rx3;
                char* trow = smem + TTB + p*8192 + sti*128;
                *(u32x4*)(trow + ((stc*32     ) ^ swt)) = rt0;
                *(u32x4*)(trow + ((stc*32 + 16) ^ swt)) = rt1;
            }
            if (jt < 15) {
                const unsigned short* g = gxb + (jt + 1)*64;
                rx0 = *(const u32x4*)(g);      rx1 = *(const u32x4*)(g + 8);
                rx2 = *(const u32x4*)(g + 16); rx3 = *(const u32x4*)(g + 24);
                const unsigned short* gT = gtb + (jt + 1)*64;
                rt0 = *(const u32x4*)(gT);     rt1 = *(const u32x4*)(gT + 8);
            }
            __syncthreads();
            const char* rA0 = smem + XTB + p*16384 + fA0*128;
            const char* rA1 = smem + XTB + p*16384 + fA1*128;
            const char* rBh = smem + TTB + p*8192  + iB*128;
#pragma unroll
            for (int kk = 0; kk < 4; ++kk) {
                const unsigned off = kk*32 + kg*16;
                bf16x8 a0 = ldfrag(rA0 + (off ^ sA0));
                bf16x8 a1 = ldfrag(rA1 + (off ^ sA1));
                bf16x8 bh = ldfrag(rBh + (off ^ sB));
                acc0 = __builtin_amdgcn_mfma_f32_32x32x16_bf16(a0, bh, acc0, 0, 0, 0);
                acc1 = __builtin_amdgcn_mfma_f32_32x32x16_bf16(a1, bh, acc1, 0, 0, 0);
            }
        }
    } else {
        const int sf0 = t >> 3, sc8 = t & 7;
        const unsigned short* gxb = xT + ((size_t)b*16 + sf0)*1024 + sc8*8;
        u32x4 rxa = {0,0,0,0};
        if (t < 128) rxa = *(const u32x4*)gxb;
        const unsigned swx0 = swz3(sf0) << 4;
        const unsigned sA = swz3(fA0) << 4;

        for (int jt = 0; jt < 16; ++jt) {
            const int p = jt & 1;
            if (t < 128)
                *(u32x4*)(smem + XT0B + p*2048 + sf0*128 + ((sc8*16) ^ swx0)) = rxa;
            {
                char* trow = smem + TT0B + p*8192 + sti*128;
                *(u32x4*)(trow + ((stc*32     ) ^ swt)) = rt0;
                *(u32x4*)(trow + ((stc*32 + 16) ^ swt)) = rt1;
            }
            if (jt < 15) {
                if (t < 128) rxa = *(const u32x4*)(gxb + (jt + 1)*64);
                const unsigned short* gT = gtb + (jt + 1)*64;
                rt0 = *(const u32x4*)(gT);  rt1 = *(const u32x4*)(gT + 8);
            }
            __syncthreads();
            const char* rA  = smem + XT0B + p*2048 + fA0*128;
            const char* rBh = smem + TT0B + p*8192 + iB*128;
#pragma unroll
            for (int kk = 0; kk < 2; ++kk) {
                const unsigned off = kk*64 + kg4*16;
                bf16x8 a  = ldfrag(rA  + (off ^ sA));
                bf16x8 bh = ldfrag(rBh + (off ^ sB));
                acc4 = __builtin_amdgcn_mfma_f32_16x16x32_bf16(a, bh, acc4, 0, 0, 0);
            }
        }
    }
    __syncthreads();   // main loop done; LDS repurposed below

    // ---- write y (already normalized) to concat buffers; stage xi ----
    if constexpr (MODE) {
        char* yrow = smem + YL + iB*256;
        const unsigned swi = swz3(iB) << 4;
#pragma unroll
        for (int rq = 0; rq < 4; ++rq) {
            unsigned q0 = (unsigned)f2bf(acc0[rq*4+0]) | ((unsigned)f2bf(acc0[rq*4+1]) << 16);
            unsigned q1 = (unsigned)f2bf(acc0[rq*4+2]) | ((unsigned)f2bf(acc0[rq*4+3]) << 16);
            u32x2 w0 = {q0, q1};
            *(u32x2*)(yrow + ((wf*128 + rq*16 + kg*8) ^ swi)) = w0;
            unsigned r0 = (unsigned)f2bf(acc1[rq*4+0]) | ((unsigned)f2bf(acc1[rq*4+1]) << 16);
            unsigned r1 = (unsigned)f2bf(acc1[rq*4+2]) | ((unsigned)f2bf(acc1[rq*4+3]) << 16);
            u32x2 w1 = {r0, r1};
            *(u32x2*)(yrow + ((wf*128 + 64 + rq*16 + kg*8) ^ swi)) = w1;
        }
        const int xi_i = t >> 2, xq = t & 3;
        const unsigned short* gx = xR + ((size_t)(b*1024 + i0g + xi_i))*128 + xq*32;
        char* xrow = smem + XI + xi_i*256;
        const unsigned swxi = swz3(xi_i) << 4;
#pragma unroll
        for (int g = 0; g < 4; ++g) {
            u32x4 v = *(const u32x4*)(gx + g*8);
            *(u32x4*)(xrow + ((xq*64 + g*16) ^ swxi)) = v;
        }
        {   // stage WT part A (f 0..127)
            const int h = t >> 2, q = t & 3;
            const unsigned short* gw = WThi + h*256 + q*32;
            char* wrow = smem + WTB + h*256;
            const unsigned sw = swz3(h) << 4;
#pragma unroll
            for (int g = 0; g < 4; ++g) {
                u32x4 v = *(const u32x4*)(gw + g*8);
                *(u32x4*)(wrow + ((q*64 + g*16) ^ sw)) = v;
            }
        }
    } else {
        unsigned q0 = (unsigned)f2bf(acc4[0]) | ((unsigned)f2bf(acc4[1]) << 16);
        unsigned q1 = (unsigned)f2bf(acc4[2]) | ((unsigned)f2bf(acc4[3]) << 16);
        u32x2 w0 = {q0, q1};
        *(u32x2*)(smem + C0O + iB*64 + ((kg4*8) ^ ((swz3(iB) & 3) << 4))) = w0;
        const int xi_i = t >> 2, xq = t & 3;
        const unsigned short* gx = xR + ((size_t)(b*1024 + i0g + xi_i))*16 + xq*4;
        u32x2 v = *(const u32x2*)gx;
        *(u32x2*)(smem + C0O + xi_i*64 + ((32 + xq*8) ^ ((swz3(xi_i) & 3) << 4))) = v;
        if (t < 128) {   // stage W0T
            const int h = t >> 1, hf = t & 1;
            const unsigned short* gw = WThi + h*32 + hf*16;
            char* wrow = smem + W0H + h*64;
            const unsigned sw2 = (swz3(h) & 3) << 4;
#pragma unroll
            for (int g = 0; g < 2; ++g) {
                u32x4 v2 = *(const u32x4*)(gw + g*8);
                *(u32x4*)(wrow + (((hf*2 + g)*16) ^ sw2)) = v2;
            }
        }
    }
    __syncthreads();

    // ---- dense: z^T = WT @ concat^T ----
    f32x16 dacc; f32x4 da0, da1, da2, da3;
#pragma unroll
    for (int r = 0; r < 16; ++r) dacc[r] = bv;
#pragma unroll
    for (int r = 0; r < 4; ++r) { da0[r] = bv; da1[r] = bv; da2[r] = bv; da3[r] = bv; }

    if constexpr (MODE) {
        const int hA = wf*32 + m31;
        const char* rWh = smem + WTB + hA*256;  const unsigned sH = swz3(hA) << 4;
        const char* rBY = smem + YL + iB*256;   const unsigned sI = swz3(iB) << 4;
#pragma unroll
        for (int k8 = 0; k8 < 8; ++k8) {
            const unsigned off = k8*32 + kg*16;
            bf16x8 ah = ldfrag(rWh + (off ^ sH));
            bf16x8 bb = ldfrag(rBY + (off ^ sI));
            dacc = __builtin_amdgcn_mfma_f32_32x32x16_bf16(ah, bb, dacc, 0, 0, 0);
        }
        __syncthreads();
        {   // stage WT part B (f 128..255)
            const int h = t >> 2, q = t & 3;
            const unsigned short* gw = WThi + h*256 + 128 + q*32;
            char* wrow = smem + WTB + h*256;
            const unsigned sw = swz3(h) << 4;
#pragma unroll
            for (int g = 0; g < 4; ++g) {
                u32x4 v = *(const u32x4*)(gw + g*8);
                *(u32x4*)(wrow + ((q*64 + g*16) ^ sw)) = v;
            }
        }
        __syncthreads();
        const char* rBX = smem + XI + iB*256;
#pragma unroll
        for (int k8 = 0; k8 < 8; ++k8) {
            const unsigned off = k8*32 + kg*16;
            bf16x8 ah = ldfrag(rWh + (off ^ sH));
            bf16x8 bb = ldfrag(rBX + (off ^ sI));
            dacc = __builtin_amdgcn_mfma_f32_32x32x16_bf16(ah, bb, dacc, 0, 0, 0);
        }
        __syncthreads();
    } else {
        const int hA = w*16 + m15;
        const unsigned sH2 = (swz3(hA) & 3) << 4;
        bf16x8 ah = ldfrag(smem + W0H + hA*64 + ((kg4*16) ^ sH2));
        {
            const int i0 = m15;
            bf16x8 b0 = ldfrag(smem + C0O + (i0     )*64 + ((kg4*16) ^ ((swz3(i0     ) & 3) << 4)));
            bf16x8 b1 = ldfrag(smem + C0O + (i0 + 16)*64 + ((kg4*16) ^ ((swz3(i0 + 16) & 3) << 4)));
            bf16x8 b2 = ldfrag(smem + C0O + (i0 + 32)*64 + ((kg4*16) ^ ((swz3(i0 + 32) & 3) << 4)));
            bf16x8 b3 = ldfrag(smem + C0O + (i0 + 48)*64 + ((kg4*16) ^ ((swz3(i0 + 48) & 3) << 4)));
            da0 = __builtin_amdgcn_mfma_f32_16x16x32_bf16(ah, b0, da0, 0, 0, 0);
            da1 = __builtin_amdgcn_mfma_f32_16x16x32_bf16(ah, b1, da1, 0, 0, 0);
            da2 = __builtin_amdgcn_mfma_f32_16x16x32_bf16(ah, b2, da2, 0, 0, 0);
            da3 = __builtin_amdgcn_mfma_f32_16x16x32_bf16(ah, b3, da3, 0, 0, 0);
        }
        __syncthreads();
    }

    // ---- epilogue ----
    float* zt = (float*)(smem + ZT);
    if constexpr (MODE == 2) {
        if (wf == 0) {
#pragma unroll
            for (int r = 0; r < 4; ++r) {
                float v = dacc[r];
                v += __shfl_xor(v, 1);  v += __shfl_xor(v, 2);  v += __shfl_xor(v, 4);
                v += __shfl_xor(v, 8);  v += __shfl_xor(v, 16);
                if (l == 0) ((float*)(smem + SPT))[w*4 + r] = v;
            }
        }
        __syncthreads();
        if (t < 4) {
            const float* sp = (const float*)(smem + SPT);
            part[((size_t)b*16 + it)*4 + t] = sp[t] + sp[4 + t];
        }
        return;
    } else {
        const float bns = rsqrtf(1.f + 1e-3f);
        if constexpr (MODE) {
#pragma unroll
            for (int r = 0; r < 16; ++r) {
                const int h = wf*32 + (r & 3) + 8*(r >> 2) + 4*kg;
                zt[h*65 + iB] = dacc[r] * (gamma[h] * bns) + beta[h];
            }
        } else {
#pragma unroll
            for (int r = 0; r < 4; ++r) {
                const int h = w*16 + kg4*4 + r;
                const float gs = gamma[h] * bns, bt = beta[h];
                zt[h*65 + (m15     )] = da0[r] * gs + bt;
                zt[h*65 + (m15 + 16)] = da1[r] * gs + bt;
                zt[h*65 + (m15 + 32)] = da2[r] * gs + bt;
                zt[h*65 + (m15 + 48)] = da3[r] * gs + bt;
            }
        }
        __syncthreads();
        // emit next-layer planes: xT' [128][1024], xR' [1024][128]
        {
            const int h = t & 63, ic = (t >> 6) * 16;
            const float* zr = zt + h*65 + ic;
            unsigned pz[8], pr[8];
#pragma unroll
            for (int q = 0; q < 8; ++q) {
                float z0 = zr[2*q], z1 = zr[2*q + 1];
                pz[q] = (unsigned)f2bf(z0) | ((unsigned)f2bf(z1) << 16);
                pr[q] = (unsigned)f2bf(fmaxf(z0, 0.f)) | ((unsigned)f2bf(fmaxf(z1, 0.f)) << 16);
            }
            unsigned short* d0 = oxT + ((size_t)b*128 + h     )*1024 + i0g + ic;
            unsigned short* d1 = oxT + ((size_t)b*128 + h + 64)*1024 + i0g + ic;
            u32x4 a = {pz[0], pz[1], pz[2], pz[3]}, c = {pz[4], pz[5], pz[6], pz[7]};
            u32x4 e = {pr[0], pr[1], pr[2], pr[3]}, f = {pr[4], pr[5], pr[6], pr[7]};
            *(u32x4*)(d0) = a; *(u32x4*)(d0 + 8) = c;
            *(u32x4*)(d1) = e; *(u32x4*)(d1 + 8) = f;
        }
        {
            const int i = t >> 2, fq = t & 3;
            unsigned pk[16];
#pragma unroll
            for (int ff = 0; ff < 16; ++ff) {
                const int f0 = fq*32 + ff*2, f1 = f0 + 1;
                float v0 = (f0 < 64) ? zt[f0*65 + i] : fmaxf(zt[(f0 - 64)*65 + i], 0.f);
                float v1 = (f1 < 64) ? zt[f1*65 + i] : fmaxf(zt[(f1 - 64)*65 + i], 0.f);
                pk[ff] = (unsigned)f2bf(v0) | ((unsigned)f2bf(v1) << 16);
            }
            unsigned short* d = oxR + ((size_t)(b*1024 + i0g + i))*128 + fq*32;
            u32x4 a = {pk[0],  pk[1],  pk[2],  pk[3]};
            u32x4 c = {pk[4],  pk[5],  pk[6],  pk[7]};
            u32x4 e = {pk[8],  pk[9],  pk[10], pk[11]};
            u32x4 f = {pk[12], pk[13], pk[14], pk[15]};
            *(u32x4*)(d)      = a; *(u32x4*)(d + 8)  = c;
            *(u32x4*)(d + 16) = e; *(u32x4*)(d + 24) = f;
        }
    }
}

__global__ void finalize_kernel(const float* __restrict__ part, const float* __restrict__ b3,
                                float* __restrict__ out)
{
    const int b = threadIdx.x;
    if (b < 32) {
        float v[4] = {0.f, 0.f, 0.f, 0.f};
        for (int i = 0; i < 16; ++i)
#pragma unroll
            for (int h = 0; h < 4; ++h) v[h] += part[((size_t)b*16 + i)*4 + h];
        const float bb = b3[0];
#pragma unroll
        for (int h = 0; h < 4; ++h) v[h] = v[h] * (1.f / 1024.f) + bb;
        const float m = fmaxf(fmaxf(v[0], v[1]), fmaxf(v[2], v[3]));
        float e[4], se = 0.f;
#pragma unroll
        for (int h = 0; h < 4; ++h) { e[h] = __expf(v[h] - m); se += e[h]; }
        const float inv = 1.f / se;
#pragma unroll
        for (int h = 0; h < 4; ++h) out[b*4 + h] = e[h] * inv;
    }
}

extern "C" void kernel_launch(void* const* d_in, const int* in_sizes, int n_in,
                              void* d_out, int out_size, void* d_ws, size_t ws_size,
                              hipStream_t stream)
{
    const float* x   = (const float*)d_in[0];
    const float* co  = (const float*)d_in[1];
    const float* psq = (const float*)d_in[2];
    const float* W0  = (const float*)d_in[3];
    const float* W1  = (const float*)d_in[4];
    const float* W2  = (const float*)d_in[5];
    const float* W3  = (const float*)d_in[6];
    const float* b0  = (const float*)d_in[7];
    const float* b1  = (const float*)d_in[8];
    const float* b2  = (const float*)d_in[9];
    const float* b3  = (const float*)d_in[10];
    const float* g0  = (const float*)d_in[11];
    const float* be0 = (const float*)d_in[12];
    const float* g1  = (const float*)d_in[13];
    const float* be1 = (const float*)d_in[14];
    const float* g2  = (const float*)d_in[15];
    const float* be2 = (const float*)d_in[16];

    char* ws = (char*)d_ws;
    const size_t MB = (size_t)1 << 20;
    unsigned short* Tg  = (unsigned short*)(ws);             // 64 MB (normalized P)
    unsigned short* xTa = (unsigned short*)(ws + 64*MB);     // 8 MB each
    unsigned short* xRa = (unsigned short*)(ws + 72*MB);
    unsigned short* xTb = (unsigned short*)(ws + 80*MB);
    unsigned short* xRb = (unsigned short*)(ws + 88*MB);
    unsigned short* xT0 = (unsigned short*)(ws + 96*MB);     // 1 MB
    unsigned short* xR0 = (unsigned short*)(ws + 97*MB);     // 1 MB
    unsigned short* wt  = (unsigned short*)(ws + 98*MB);     // 100 KB
    float* part         = (float*)(ws + 98*MB + 256*1024);   // 8 KB

    unsigned short* WT0 = wt;
    unsigned short* WT1 = wt + 2048;
    unsigned short* WT2 = wt + 18432;
    unsigned short* WT3 = wt + 34816;

    prep<<<dim3(328), 256, 0, stream>>>(W0, W1, W2, W3, x, wt, xT0, xR0);
    tgen<<<dim3(64, 32), 256, 0, stream>>>(co, psq, Tg);

    dim3 grid(16, 32);
    gcn_block<0><<<grid, 256, 0, stream>>>(xT0, xR0, Tg, WT0, g0, be0, b0, xTa, xRa, nullptr);
    gcn_block<1><<<grid, 256, 0, stream>>>(xTa, xRa, Tg, WT1, g1, be1, b1, xTb, xRb, nullptr);
    gcn_block<1><<<grid, 256, 0, stream>>>(xTb, xRb, Tg, WT2, g2, be2, b2, xTa, xRa, nullptr);
    gcn_block<2><<<grid, 256, 0, stream>>>(xTa, xRa, Tg, WT3, nullptr, nullptr, nullptr,
                                           nullptr, nullptr, part);
    finalize_kernel<<<1, 64, 0, stream>>>(part, b3, (float*)d_out);
}